// Round 16
// baseline (6035.982 us; speedup 1.0000x reference)
//
#include <hip/hip_runtime.h>
#include <hip/hip_bf16.h>
#include <cstdint>

typedef __attribute__((ext_vector_type(8))) short short8;
typedef __attribute__((ext_vector_type(4))) float f32x4;
typedef __attribute__((ext_vector_type(4))) short short4v;

__device__ __forceinline__ float b2f(short s) {
    unsigned u = ((unsigned)(unsigned short)s) << 16;
    return __builtin_bit_cast(float, u);
}
__device__ __forceinline__ short f2b(float f) {
    unsigned u = __builtin_bit_cast(unsigned, f);
    u += 0x7fff + ((u >> 16) & 1);   // RNE
    return (short)(u >> 16);
}

// tanh-form GELU, 8-VALU: gelu = x - x/(1+exp2(x*(c1 + c2*x^2)))
__device__ __forceinline__ float gelu_t(float x) {
    const float c1 = 2.302184829f;     // 2*log2(e)*0.7978845608
    const float c2 = 0.102947246f;     // c1 * 0.044715
    float x2 = x * x;
    float t  = __builtin_fmaf(c2, x2, c1);
    float e  = __builtin_amdgcn_exp2f(x * t);
    return x - __fdividef(x, e + 1.0f);
}

__device__ __forceinline__ void async16(const void* g, void* l) {
    __builtin_amdgcn_global_load_lds(
        (const __attribute__((address_space(1))) unsigned int*)g,
        (__attribute__((address_space(3))) unsigned int*)l, 16, 0, 0);
}

// =====================================================================
// 256x256-tile GEMM, K=512, counted-vmcnt pipeline, BK=32:
//  - LDS 64 KB total (2 bufs x 32 KB) -> 2 blocks/CU: prologue/epilogue
//    of one block hides under the other's K-loop (m114 overlap)
//  - 64-B LDS rows, XOR key ((row>>1)&3): 2-way max = free (derived)
//  - raw s_barrier + "s_waitcnt vmcnt(4)" (never 0 mid-loop), setprio
// =====================================================================
#define NT 16   // K-tiles (512 / 32)

template<bool GELU>
__global__ __launch_bounds__(512, 4)
void gemm_bt(const short* __restrict__ A, long sA,
             const short* __restrict__ Bt, long sB,
             const float* __restrict__ bias, long sBias,
             short* __restrict__ C, long sC) {
    const int z = blockIdx.z;
    A    += (long)z * sA;
    Bt   += (long)z * sB;
    bias += (long)z * sBias;
    C    += (long)z * sC;

    const int nwg = (int)gridDim.x;
    const int bx  = (int)blockIdx.x;
    int flat = bx;
    if ((nwg & 7) == 0) { const int q = nwg >> 3; flat = (bx & 7) * q + (bx >> 3); }
    const long arow0 = (long)(flat >> 1) * 256;
    const long brow0 = (long)(flat & 1) * 256;

    // 2 buffers x (A 256x32 + B 256x32 shorts) = 65536 B
    __shared__ alignas(16) short smem[2 * 2 * 256 * 32];

    const int tid  = threadIdx.x;
    const int lane = tid & 63;
    const int w    = tid >> 6;
    const int wrow = w >> 2, wcol = w & 3;
    const int lr = lane & 15, hi = lane >> 4;

    f32x4 acc[8][4] = {};

    // staging: lane covers 16 rows x 4 chunks; LDS dest lane-linear;
    // global source chunk pre-swizzled with key = ((row>>1)&3)
    const int sr16 = lane >> 2;           // 0..15 row within 16-group
    const int sch  = lane & 3;            // 16B chunk

    auto stage = [&](int q, int t) {
        short* Ab = smem + q * 16384;
        short* Bb = Ab + 8192;
        const int k0 = t * 32;
#pragma unroll
        for (int j = 0; j < 2; ++j) {
            const int rbase = w * 32 + j * 16;          // wave-uniform
            const int row = rbase + sr16;
            const int gc  = sch ^ ((row >> 1) & 3);     // pre-swizzled chunk
            async16(A  + (arow0 + row) * 512 + k0 + gc * 8, Ab + rbase * 32);
            async16(Bt + (brow0 + row) * 512 + k0 + gc * 8, Bb + rbase * 32);
        }
    };

    stage(0, 0);

    int buf = 0;
#pragma unroll
    for (int t = 0; t < NT; ++t) {
        if (t + 1 < NT) {
            stage(buf ^ 1, t + 1);
            asm volatile("s_waitcnt vmcnt(4)" ::: "memory");   // tile t landed; t+1 in flight
        } else {
            asm volatile("s_waitcnt vmcnt(0)" ::: "memory");
        }
        __builtin_amdgcn_sched_barrier(0);
        __builtin_amdgcn_s_barrier();
        __builtin_amdgcn_sched_barrier(0);

        const short* Ab = smem + buf * 16384;
        const short* Bb = Ab + 8192;
        short8 a[8], b[4];
#pragma unroll
        for (int n = 0; n < 4; ++n) {
            const int r = wcol * 64 + n * 16 + lr;
            b[n] = *(const short8*)&Bb[r * 32 + ((hi ^ ((r >> 1) & 3)) * 8)];
        }
#pragma unroll
        for (int m = 0; m < 8; ++m) {
            const int r = wrow * 128 + m * 16 + lr;
            a[m] = *(const short8*)&Ab[r * 32 + ((hi ^ ((r >> 1) & 3)) * 8)];
        }
        __builtin_amdgcn_s_setprio(1);
#pragma unroll
        for (int m = 0; m < 8; ++m)
#pragma unroll
            for (int n = 0; n < 4; ++n)
                acc[m][n] = __builtin_amdgcn_mfma_f32_16x16x32_bf16(
                    a[m], b[n], acc[m][n], 0, 0, 0);
        __builtin_amdgcn_s_setprio(0);

        __builtin_amdgcn_s_barrier();
        buf ^= 1;
    }

    // ---- epilogue: 4 half-passes of 32 rows; wave-private E = [32][72] ----
    short* E = smem + w * (32 * 72);       // 8*2304 = 18432 shorts <= 32768
    const int cl = lr, rl = hi * 4;
#pragma unroll
    for (int h = 0; h < 4; ++h) {
#pragma unroll
        for (int n = 0; n < 4; ++n) {
            const int col = (int)brow0 + wcol * 64 + n * 16 + cl;
            const float bs = bias[col];
            const int ecol = n * 16 + cl;
#pragma unroll
            for (int ml = 0; ml < 2; ++ml) {
                const int m = h * 2 + ml;
                float g0 = acc[m][n][0] + bs, g1 = acc[m][n][1] + bs;
                float g2 = acc[m][n][2] + bs, g3 = acc[m][n][3] + bs;
                if (GELU) { g0 = gelu_t(g0); g1 = gelu_t(g1); g2 = gelu_t(g2); g3 = gelu_t(g3); }
                unsigned p01, p23;
                asm("v_cvt_pk_bf16_f32 %0, %1, %2" : "=v"(p01) : "v"(g0), "v"(g1));
                asm("v_cvt_pk_bf16_f32 %0, %1, %2" : "=v"(p23) : "v"(g2), "v"(g3));
                const int r0 = ml * 16 + rl;
                E[(r0 + 0) * 72 + ecol] = (short)(p01 & 0xffff);
                E[(r0 + 1) * 72 + ecol] = (short)(p01 >> 16);
                E[(r0 + 2) * 72 + ecol] = (short)(p23 & 0xffff);
                E[(r0 + 3) * 72 + ecol] = (short)(p23 >> 16);
            }
        }
#pragma unroll
        for (int chunk = 0; chunk < 4; ++chunk) {
            const int rloc = chunk * 8 + (lane >> 3);
            const int c0   = (lane & 7) * 8;
            short8 v = *(const short8*)&E[rloc * 72 + c0];
            *(short8*)&C[(arow0 + wrow * 128 + h * 32 + rloc) * 512
                         + brow0 + wcol * 64 + c0] = v;
        }
    }
}

// ---- transpose+convert: dst[n][k] = bf16(src[k][n]), one 512x512 per blockIdx.z ----
__global__ __launch_bounds__(256)
void transpose_conv(const float* __restrict__ src, short* __restrict__ dst) {
    __shared__ float t[32][33];
    const long moff = (long)blockIdx.z * 512 * 512;
    const float* s = src + moff;
    short* d = dst + moff;
    const int tx = threadIdx.x & 31, ty = threadIdx.x >> 5;
    const int bi = blockIdx.x, bj = blockIdx.y;
#pragma unroll
    for (int j = 0; j < 4; ++j)
        t[ty + j * 8][tx] = s[(long)(bi * 32 + ty + j * 8) * 512 + bj * 32 + tx];
    __syncthreads();
#pragma unroll
    for (int j = 0; j < 4; ++j)
        d[(long)(bj * 32 + ty + j * 8) * 512 + bi * 32 + tx] = f2b(t[tx][ty + j * 8]);
}

// ---- f32 -> bf16 elementwise ----
__global__ __launch_bounds__(256)
void conv_f32_bf16(const float* __restrict__ src, short* __restrict__ dst, long n) {
    long i = ((long)blockIdx.x * 256 + threadIdx.x) * 4;
    if (i >= n) return;
    float4 f = *(const float4*)&src[i];
    short4v o;
    o[0] = f2b(f.x); o[1] = f2b(f.y); o[2] = f2b(f.z); o[3] = f2b(f.w);
    *(short4v*)&dst[i] = o;
}

// ---- bias fold: bB[(k+1)*512+n] = dot(tb3_k, eW1[:,n]) + eb1[n] ----
__global__ __launch_bounds__(256)
void bias_fold(const float* __restrict__ tb3, const short* __restrict__ wtE1,
               const float* __restrict__ eb1, float* __restrict__ bB) {
    const int wid = threadIdx.x >> 6, lane = threadIdx.x & 63;
    const int idx = blockIdx.x * 4 + wid;        // 0 .. 11*512-1
    const int k = idx >> 9, n = idx & 511;
    short8 wv = *(const short8*)&wtE1[(long)n * 512 + lane * 8];
    const float* tb = tb3 + (long)k * 512 + lane * 8;
    float s = 0.f;
#pragma unroll
    for (int j = 0; j < 8; ++j) s += b2f(wv[j]) * tb[j];
#pragma unroll
    for (int o = 1; o < 64; o <<= 1) s += __shfl_xor(s, o, 64);
    if (lane == 0) bB[(long)(k + 1) * 512 + n] = s + eb1[n];
}

// ---- fused LN + L2-normalize + MFMA Gram + logsumexp loss (r12-proven) ----
__global__ __launch_bounds__(256)
void ln_loss(const short* __restrict__ H, const float* __restrict__ g,
             const float* __restrict__ bta, float* __restrict__ out, int CH) {
    __shared__ alignas(16) short Z[4][16 * 520];
    const int wid = threadIdx.x >> 6, lane = threadIdx.x & 63;
    const long b = (long)blockIdx.x * 4 + wid;
    short* Zw = &Z[wid][0];

#pragma unroll
    for (int r = 12; r < 16; ++r)
        *(short8*)&Zw[r * 520 + lane * 8] = (short8){0, 0, 0, 0, 0, 0, 0, 0};

    for (int s = 0; s < 12; ++s) {
        short8 t = *(const short8*)&H[((long)s * CH + b) * 512 + lane * 8];
        float v[8];
        float sum = 0.f, ss = 0.f;
#pragma unroll
        for (int j = 0; j < 8; ++j) { v[j] = b2f(t[j]); sum += v[j]; ss += v[j] * v[j]; }
#pragma unroll
        for (int o = 1; o < 64; o <<= 1) { sum += __shfl_xor(sum, o, 64); ss += __shfl_xor(ss, o, 64); }
        const float mu = sum * (1.f / 512.f);
        const float rs = rsqrtf(ss * (1.f / 512.f) - mu * mu + 1e-5f);
        float y[8]; float nsq = 0.f;
#pragma unroll
        for (int j = 0; j < 8; ++j) {
            const int col = lane * 8 + j;
            y[j] = (v[j] - mu) * rs * g[col] + bta[col];
            nsq += y[j] * y[j];
        }
#pragma unroll
        for (int o = 1; o < 64; o <<= 1) nsq += __shfl_xor(nsq, o, 64);
        const float inv = 1.f / fmaxf(sqrtf(nsq), 1e-8f);
        short8 o8;
#pragma unroll
        for (int j = 0; j < 8; ++j) o8[j] = f2b(y[j] * inv);
        *(short8*)&Zw[s * 520 + lane * 8] = o8;
    }

    f32x4 acc = {0.f, 0.f, 0.f, 0.f};
    const int lr = lane & 15, hi = lane >> 4;
#pragma unroll
    for (int st = 0; st < 16; ++st) {
        short8 a = *(const short8*)&Zw[lr * 520 + st * 32 + hi * 8];
        acc = __builtin_amdgcn_mfma_f32_16x16x32_bf16(a, a, acc, 0, 0, 0);
    }
    const int col = lr;
    float lmax = -3.0e38f;
    bool valid[4];
#pragma unroll
    for (int i = 0; i < 4; ++i) {
        const int row = hi * 4 + i;
        valid[i] = (row < 12) && (row != col);
        if (valid[i]) lmax = fmaxf(lmax, acc[i]);
    }
    lmax = fmaxf(lmax, __shfl_xor(lmax, 16, 64));
    lmax = fmaxf(lmax, __shfl_xor(lmax, 32, 64));
    float esum = 0.f;
#pragma unroll
    for (int i = 0; i < 4; ++i)
        if (valid[i]) esum += __builtin_amdgcn_exp2f((acc[i] - lmax) * 1.44269504f);
    esum += __shfl_xor(esum, 16, 64);
    esum += __shfl_xor(esum, 32, 64);
    float contrib = 0.f;
    if (hi == 0 && col >= 1 && col <= 11) {
        const float logden = lmax + __builtin_amdgcn_logf(esum) * 0.6931471806f;
        contrib = acc[0] - logden;
    }
#pragma unroll
    for (int o = 1; o < 16; o <<= 1) contrib += __shfl_xor(contrib, o, 64);
    if (lane == 0) out[b] = -contrib;
}

// ---------------- host ----------------
extern "C" void kernel_launch(void* const* d_in, const int* in_sizes, int n_in,
                              void* d_out, int out_size, void* d_ws, size_t ws_size,
                              hipStream_t stream) {
    const float* x    = (const float*)d_in[0];
    const float* tW1  = (const float*)d_in[1];
    const float* tb1  = (const float*)d_in[2];
    const float* tW2  = (const float*)d_in[3];
    const float* tb2  = (const float*)d_in[4];
    const float* tW3  = (const float*)d_in[5];
    const float* tb3  = (const float*)d_in[6];
    const float* eW1  = (const float*)d_in[7];
    const float* eb1  = (const float*)d_in[8];
    const float* eW2  = (const float*)d_in[9];
    const float* eb2  = (const float*)d_in[10];
    const float* eW3  = (const float*)d_in[11];
    const float* eb3  = (const float*)d_in[12];
    const float* ln_g = (const float*)d_in[13];
    const float* ln_b = (const float*)d_in[14];

    const int  B    = in_sizes[0] / 512;   // 16384
    const long WMAT = 512L * 512L;

    int  c  = 1;
    long CH = B;
    for (;;) {
        CH = (long)B / c;
        size_t need = (size_t)48 * WMAT * 2 + (512 + 12 * 512) * 4
                    + (size_t)24 * CH * 512 * 2 + 8192;
        if (need <= ws_size || CH <= 256) break;
        c <<= 1;
    }
    const long SLAB = 12L * CH * 512;

    short* wt   = (short*)d_ws;             // 0..21: tW1^T,tW2^T; 22..32: tW3 (orig); 33..35: eW^T
    short* Mt   = wt + 36L * WMAT;          // slot0 = eW1^T, 1..11 = (tW3_k·eW1)^T
    float* zero512 = (float*)(Mt + 12L * WMAT);
    float* bB   = zero512 + 512;            // 12x512 folded biases
    short* S    = (short*)(bB + 12 * 512);  // slab S [12, CH, 512]
    short* T    = S + SLAB;                 // slab T [12, CH, 512]

    // --- weight prep (once per launch) ---
    {
        dim3 tgK(16, 16, 11), tg1(16, 16, 1);
        transpose_conv<<<tgK, 256, 0, stream>>>(tW1, wt + 0L * WMAT);
        transpose_conv<<<tgK, 256, 0, stream>>>(tW2, wt + 11L * WMAT);
        conv_f32_bf16<<<(unsigned)((11 * WMAT / 4 + 255) / 256), 256, 0, stream>>>(
            tW3, wt + 22L * WMAT, 11 * WMAT);
        transpose_conv<<<tg1, 256, 0, stream>>>(eW1, wt + 33L * WMAT);
        transpose_conv<<<tg1, 256, 0, stream>>>(eW2, wt + 34L * WMAT);
        transpose_conv<<<tg1, 256, 0, stream>>>(eW3, wt + 35L * WMAT);

        hipMemsetAsync(zero512, 0, 512 * sizeof(float), stream);
        gemm_bt<false><<<dim3(4, 1, 11), 512, 0, stream>>>(
            wt + 33L * WMAT, 0, wt + 22L * WMAT, WMAT, zero512, 0, Mt + WMAT, WMAT);
        hipMemcpyAsync(Mt, wt + 33L * WMAT, WMAT * sizeof(short),
                       hipMemcpyDeviceToDevice, stream);
        hipMemcpyAsync(bB, eb1, 512 * sizeof(float),
                       hipMemcpyDeviceToDevice, stream);
        bias_fold<<<(11 * 512) / 4, 256, 0, stream>>>(tb3, wt + 33L * WMAT, eb1, bB);
    }

    const long SC = CH * 512;
    const dim3 gT((unsigned)(CH / 256 * 2), 1, 11);       // L1,L2: M = CH
    const dim3 gF((unsigned)(CH / 256 * 2), 1, 12);       // fold pass: 12 views
    const dim3 gE((unsigned)(12 * CH / 256 * 2), 1, 1);   // E2,E3: M = 12*CH

    for (int ch = 0; ch < c; ++ch) {
        conv_f32_bf16<<<(unsigned)((SC / 4 + 255) / 256), 256, 0, stream>>>(
            x + (long)ch * SC, S, SC);

        gemm_bt<true ><<<gT, 512, 0, stream>>>(S, 0,  wt + 0L * WMAT,  WMAT, tb1, 512, T + SC, SC);
        gemm_bt<true ><<<gT, 512, 0, stream>>>(T + SC, SC, wt + 11L * WMAT, WMAT, tb2, 512, S + SC, SC);
        gemm_bt<true ><<<gF, 512, 0, stream>>>(S, SC, Mt, WMAT, bB, 512, T, SC);
        gemm_bt<true ><<<gE, 512, 0, stream>>>(T, 0, wt + 34L * WMAT, 0, eb2, 0, S, 0);
        gemm_bt<false><<<gE, 512, 0, stream>>>(S, 0, wt + 35L * WMAT, 0, eb3, 0, T, 0);

        ln_loss<<<(unsigned)(CH / 4), 256, 0, stream>>>(
            T, ln_g, ln_b, (float*)d_out + (long)ch * CH, (int)CH);
    }
}

// Round 17
// 1024.889 us; speedup vs baseline: 5.8894x; 5.8894x over previous
//
#include <hip/hip_runtime.h>
#include <hip/hip_bf16.h>
#include <cstdint>

typedef __attribute__((ext_vector_type(8))) short short8;
typedef __attribute__((ext_vector_type(4))) float f32x4;
typedef __attribute__((ext_vector_type(4))) short short4v;

__device__ __forceinline__ float b2f(short s) {
    unsigned u = ((unsigned)(unsigned short)s) << 16;
    return __builtin_bit_cast(float, u);
}
__device__ __forceinline__ short f2b(float f) {
    unsigned u = __builtin_bit_cast(unsigned, f);
    u += 0x7fff + ((u >> 16) & 1);   // RNE
    return (short)(u >> 16);
}

// tanh-form GELU, 8-VALU: gelu = x - x/(1+exp2(x*(c1 + c2*x^2)))
__device__ __forceinline__ float gelu_t(float x) {
    const float c1 = 2.302184829f;     // 2*log2(e)*0.7978845608
    const float c2 = 0.102947246f;     // c1 * 0.044715
    float x2 = x * x;
    float t  = __builtin_fmaf(c2, x2, c1);
    float e  = __builtin_amdgcn_exp2f(x * t);
    return x - __fdividef(x, e + 1.0f);
}

__device__ __forceinline__ void async16(const void* g, void* l) {
    __builtin_amdgcn_global_load_lds(
        (const __attribute__((address_space(1))) unsigned int*)g,
        (__attribute__((address_space(3))) unsigned int*)l, 16, 0, 0);
}

// =====================================================================
// 256x128-tile GEMM, K=512, counted-vmcnt pipeline, BK=32:
//  - 8 waves (4M x 2N), per-wave output 64x64 -> acc[4][4] = 64 VGPR
//    => ~110 VGPR total, 48 KB LDS => TWO blocks/CU resident (m114
//    cross-block overlap; 2x HBM requests in flight). NO forced
//    launch_bounds min-waves (r16 lesson: that spills the accumulator).
//  - raw s_barrier + "s_waitcnt vmcnt(3)" (never 0 mid-loop), setprio
// =====================================================================
#define NT 16   // K-tiles (512 / 32)

template<bool GELU>
__global__ __launch_bounds__(512)
void gemm_bt(const short* __restrict__ A, long sA,
             const short* __restrict__ Bt, long sB,
             const float* __restrict__ bias, long sBias,
             short* __restrict__ C, long sC) {
    const int z = blockIdx.z;
    A    += (long)z * sA;
    Bt   += (long)z * sB;
    bias += (long)z * sBias;
    C    += (long)z * sC;

    const int nwg = (int)gridDim.x;
    const int bx  = (int)blockIdx.x;
    int flat = bx;
    if ((nwg & 7) == 0) { const int q = nwg >> 3; flat = (bx & 7) * q + (bx >> 3); }
    const long arow0 = (long)(flat >> 2) * 256;   // M-tile (256 rows)
    const long brow0 = (long)(flat & 3) * 128;    // N-tile (4 over N=512)

    // 2 buffers x (A 256x32 + B 128x32 shorts) = 49152 B
    __shared__ alignas(16) short smem[2 * (256 + 128) * 32];

    const int tid  = threadIdx.x;
    const int lane = tid & 63;
    const int w    = tid >> 6;             // 0..7
    const int wrow = w >> 1, wcol = w & 1; // 4x2 wave grid: 64 rows x 64 cols
    const int lr = lane & 15, hi = lane >> 4;

    f32x4 acc[4][4] = {};

    // staging: LDS dest lane-linear; global source chunk pre-swizzled
    // with key = ((row>>1)&3)
    const int sr16 = lane >> 2;           // 0..15 row within 16-group
    const int sch  = lane & 3;            // 16B chunk

    auto stage = [&](int q, int t) {
        short* Ab = smem + q * 12288;
        short* Bb = Ab + 8192;
        const int k0 = t * 32;
#pragma unroll
        for (int j = 0; j < 2; ++j) {                   // A: 256 rows
            const int rbase = w * 32 + j * 16;          // wave-uniform
            const int row = rbase + sr16;
            const int gc  = sch ^ ((row >> 1) & 3);
            async16(A + (arow0 + row) * 512 + k0 + gc * 8, Ab + rbase * 32);
        }
        {                                               // B: 128 rows
            const int rbase = w * 16;
            const int row = rbase + sr16;
            const int gc  = sch ^ ((row >> 1) & 3);
            async16(Bt + (brow0 + row) * 512 + k0 + gc * 8, Bb + rbase * 32);
        }
    };

    stage(0, 0);

    int buf = 0;
#pragma unroll
    for (int t = 0; t < NT; ++t) {
        if (t + 1 < NT) {
            stage(buf ^ 1, t + 1);
            asm volatile("s_waitcnt vmcnt(3)" ::: "memory");   // tile t landed; t+1 in flight
        } else {
            asm volatile("s_waitcnt vmcnt(0)" ::: "memory");
        }
        __builtin_amdgcn_sched_barrier(0);
        __builtin_amdgcn_s_barrier();
        __builtin_amdgcn_sched_barrier(0);

        const short* Ab = smem + buf * 12288;
        const short* Bb = Ab + 8192;
        short8 a[4], b[4];
#pragma unroll
        for (int n = 0; n < 4; ++n) {
            const int r = wcol * 64 + n * 16 + lr;
            b[n] = *(const short8*)&Bb[r * 32 + ((hi ^ ((r >> 1) & 3)) * 8)];
        }
#pragma unroll
        for (int m = 0; m < 4; ++m) {
            const int r = wrow * 64 + m * 16 + lr;
            a[m] = *(const short8*)&Ab[r * 32 + ((hi ^ ((r >> 1) & 3)) * 8)];
        }
        __builtin_amdgcn_s_setprio(1);
#pragma unroll
        for (int m = 0; m < 4; ++m)
#pragma unroll
            for (int n = 0; n < 4; ++n)
                acc[m][n] = __builtin_amdgcn_mfma_f32_16x16x32_bf16(
                    a[m], b[n], acc[m][n], 0, 0, 0);
        __builtin_amdgcn_s_setprio(0);

        __builtin_amdgcn_s_barrier();
        buf ^= 1;
    }

    // ---- epilogue: 2 half-passes of 32 rows; wave-private E = [32][72] ----
    short* E = smem + w * (32 * 72);       // 8*2304 = 18432 shorts <= 24576
    const int cl = lr, rl = hi * 4;
#pragma unroll
    for (int h = 0; h < 2; ++h) {
#pragma unroll
        for (int n = 0; n < 4; ++n) {
            const int col = (int)brow0 + wcol * 64 + n * 16 + cl;
            const float bs = bias[col];
            const int ecol = n * 16 + cl;
#pragma unroll
            for (int ml = 0; ml < 2; ++ml) {
                const int m = h * 2 + ml;
                float g0 = acc[m][n][0] + bs, g1 = acc[m][n][1] + bs;
                float g2 = acc[m][n][2] + bs, g3 = acc[m][n][3] + bs;
                if (GELU) { g0 = gelu_t(g0); g1 = gelu_t(g1); g2 = gelu_t(g2); g3 = gelu_t(g3); }
                unsigned p01, p23;
                asm("v_cvt_pk_bf16_f32 %0, %1, %2" : "=v"(p01) : "v"(g0), "v"(g1));
                asm("v_cvt_pk_bf16_f32 %0, %1, %2" : "=v"(p23) : "v"(g2), "v"(g3));
                const int r0 = ml * 16 + rl;
                E[(r0 + 0) * 72 + ecol] = (short)(p01 & 0xffff);
                E[(r0 + 1) * 72 + ecol] = (short)(p01 >> 16);
                E[(r0 + 2) * 72 + ecol] = (short)(p23 & 0xffff);
                E[(r0 + 3) * 72 + ecol] = (short)(p23 >> 16);
            }
        }
        // wave-private region: LDS ops in-order within a wave
#pragma unroll
        for (int chunk = 0; chunk < 4; ++chunk) {
            const int rloc = chunk * 8 + (lane >> 3);
            const int c0   = (lane & 7) * 8;
            short8 v = *(const short8*)&E[rloc * 72 + c0];
            *(short8*)&C[(arow0 + wrow * 64 + h * 32 + rloc) * 512
                         + brow0 + wcol * 64 + c0] = v;
        }
    }
}

// ---- transpose+convert: dst[n][k] = bf16(src[k][n]), one 512x512 per blockIdx.z ----
__global__ __launch_bounds__(256)
void transpose_conv(const float* __restrict__ src, short* __restrict__ dst) {
    __shared__ float t[32][33];
    const long moff = (long)blockIdx.z * 512 * 512;
    const float* s = src + moff;
    short* d = dst + moff;
    const int tx = threadIdx.x & 31, ty = threadIdx.x >> 5;
    const int bi = blockIdx.x, bj = blockIdx.y;
#pragma unroll
    for (int j = 0; j < 4; ++j)
        t[ty + j * 8][tx] = s[(long)(bi * 32 + ty + j * 8) * 512 + bj * 32 + tx];
    __syncthreads();
#pragma unroll
    for (int j = 0; j < 4; ++j)
        d[(long)(bj * 32 + ty + j * 8) * 512 + bi * 32 + tx] = f2b(t[tx][ty + j * 8]);
}

// ---- f32 -> bf16 elementwise ----
__global__ __launch_bounds__(256)
void conv_f32_bf16(const float* __restrict__ src, short* __restrict__ dst, long n) {
    long i = ((long)blockIdx.x * 256 + threadIdx.x) * 4;
    if (i >= n) return;
    float4 f = *(const float4*)&src[i];
    short4v o;
    o[0] = f2b(f.x); o[1] = f2b(f.y); o[2] = f2b(f.z); o[3] = f2b(f.w);
    *(short4v*)&dst[i] = o;
}

// ---- bias fold: bB[(k+1)*512+n] = dot(tb3_k, eW1[:,n]) + eb1[n] ----
__global__ __launch_bounds__(256)
void bias_fold(const float* __restrict__ tb3, const short* __restrict__ wtE1,
               const float* __restrict__ eb1, float* __restrict__ bB) {
    const int wid = threadIdx.x >> 6, lane = threadIdx.x & 63;
    const int idx = blockIdx.x * 4 + wid;        // 0 .. 11*512-1
    const int k = idx >> 9, n = idx & 511;
    short8 wv = *(const short8*)&wtE1[(long)n * 512 + lane * 8];
    const float* tb = tb3 + (long)k * 512 + lane * 8;
    float s = 0.f;
#pragma unroll
    for (int j = 0; j < 8; ++j) s += b2f(wv[j]) * tb[j];
#pragma unroll
    for (int o = 1; o < 64; o <<= 1) s += __shfl_xor(s, o, 64);
    if (lane == 0) bB[(long)(k + 1) * 512 + n] = s + eb1[n];
}

// ---- fused LN + L2-normalize + MFMA Gram + logsumexp loss (r12-proven) ----
__global__ __launch_bounds__(256)
void ln_loss(const short* __restrict__ H, const float* __restrict__ g,
             const float* __restrict__ bta, float* __restrict__ out, int CH) {
    __shared__ alignas(16) short Z[4][16 * 520];
    const int wid = threadIdx.x >> 6, lane = threadIdx.x & 63;
    const long b = (long)blockIdx.x * 4 + wid;
    short* Zw = &Z[wid][0];

#pragma unroll
    for (int r = 12; r < 16; ++r)
        *(short8*)&Zw[r * 520 + lane * 8] = (short8){0, 0, 0, 0, 0, 0, 0, 0};

    for (int s = 0; s < 12; ++s) {
        short8 t = *(const short8*)&H[((long)s * CH + b) * 512 + lane * 8];
        float v[8];
        float sum = 0.f, ss = 0.f;
#pragma unroll
        for (int j = 0; j < 8; ++j) { v[j] = b2f(t[j]); sum += v[j]; ss += v[j] * v[j]; }
#pragma unroll
        for (int o = 1; o < 64; o <<= 1) { sum += __shfl_xor(sum, o, 64); ss += __shfl_xor(ss, o, 64); }
        const float mu = sum * (1.f / 512.f);
        const float rs = rsqrtf(ss * (1.f / 512.f) - mu * mu + 1e-5f);
        float y[8]; float nsq = 0.f;
#pragma unroll
        for (int j = 0; j < 8; ++j) {
            const int col = lane * 8 + j;
            y[j] = (v[j] - mu) * rs * g[col] + bta[col];
            nsq += y[j] * y[j];
        }
#pragma unroll
        for (int o = 1; o < 64; o <<= 1) nsq += __shfl_xor(nsq, o, 64);
        const float inv = 1.f / fmaxf(sqrtf(nsq), 1e-8f);
        short8 o8;
#pragma unroll
        for (int j = 0; j < 8; ++j) o8[j] = f2b(y[j] * inv);
        *(short8*)&Zw[s * 520 + lane * 8] = o8;
    }

    f32x4 acc = {0.f, 0.f, 0.f, 0.f};
    const int lr = lane & 15, hi = lane >> 4;
#pragma unroll
    for (int st = 0; st < 16; ++st) {
        short8 a = *(const short8*)&Zw[lr * 520 + st * 32 + hi * 8];
        acc = __builtin_amdgcn_mfma_f32_16x16x32_bf16(a, a, acc, 0, 0, 0);
    }
    const int col = lr;
    float lmax = -3.0e38f;
    bool valid[4];
#pragma unroll
    for (int i = 0; i < 4; ++i) {
        const int row = hi * 4 + i;
        valid[i] = (row < 12) && (row != col);
        if (valid[i]) lmax = fmaxf(lmax, acc[i]);
    }
    lmax = fmaxf(lmax, __shfl_xor(lmax, 16, 64));
    lmax = fmaxf(lmax, __shfl_xor(lmax, 32, 64));
    float esum = 0.f;
#pragma unroll
    for (int i = 0; i < 4; ++i)
        if (valid[i]) esum += __builtin_amdgcn_exp2f((acc[i] - lmax) * 1.44269504f);
    esum += __shfl_xor(esum, 16, 64);
    esum += __shfl_xor(esum, 32, 64);
    float contrib = 0.f;
    if (hi == 0 && col >= 1 && col <= 11) {
        const float logden = lmax + __builtin_amdgcn_logf(esum) * 0.6931471806f;
        contrib = acc[0] - logden;
    }
#pragma unroll
    for (int o = 1; o < 16; o <<= 1) contrib += __shfl_xor(contrib, o, 64);
    if (lane == 0) out[b] = -contrib;
}

// ---------------- host ----------------
extern "C" void kernel_launch(void* const* d_in, const int* in_sizes, int n_in,
                              void* d_out, int out_size, void* d_ws, size_t ws_size,
                              hipStream_t stream) {
    const float* x    = (const float*)d_in[0];
    const float* tW1  = (const float*)d_in[1];
    const float* tb1  = (const float*)d_in[2];
    const float* tW2  = (const float*)d_in[3];
    const float* tb2  = (const float*)d_in[4];
    const float* tW3  = (const float*)d_in[5];
    const float* tb3  = (const float*)d_in[6];
    const float* eW1  = (const float*)d_in[7];
    const float* eb1  = (const float*)d_in[8];
    const float* eW2  = (const float*)d_in[9];
    const float* eb2  = (const float*)d_in[10];
    const float* eW3  = (const float*)d_in[11];
    const float* eb3  = (const float*)d_in[12];
    const float* ln_g = (const float*)d_in[13];
    const float* ln_b = (const float*)d_in[14];

    const int  B    = in_sizes[0] / 512;   // 16384
    const long WMAT = 512L * 512L;

    int  c  = 1;
    long CH = B;
    for (;;) {
        CH = (long)B / c;
        size_t need = (size_t)48 * WMAT * 2 + (512 + 12 * 512) * 4
                    + (size_t)24 * CH * 512 * 2 + 8192;
        if (need <= ws_size || CH <= 256) break;
        c <<= 1;
    }
    const long SLAB = 12L * CH * 512;

    short* wt   = (short*)d_ws;             // 0..21: tW1^T,tW2^T; 22..32: tW3 (orig); 33..35: eW^T
    short* Mt   = wt + 36L * WMAT;          // slot0 = eW1^T, 1..11 = (tW3_k·eW1)^T
    float* zero512 = (float*)(Mt + 12L * WMAT);
    float* bB   = zero512 + 512;            // 12x512 folded biases
    short* S    = (short*)(bB + 12 * 512);  // slab S [12, CH, 512]
    short* T    = S + SLAB;                 // slab T [12, CH, 512]

    // --- weight prep (once per launch) ---
    {
        dim3 tgK(16, 16, 11), tg1(16, 16, 1);
        transpose_conv<<<tgK, 256, 0, stream>>>(tW1, wt + 0L * WMAT);
        transpose_conv<<<tgK, 256, 0, stream>>>(tW2, wt + 11L * WMAT);
        conv_f32_bf16<<<(unsigned)((11 * WMAT / 4 + 255) / 256), 256, 0, stream>>>(
            tW3, wt + 22L * WMAT, 11 * WMAT);
        transpose_conv<<<tg1, 256, 0, stream>>>(eW1, wt + 33L * WMAT);
        transpose_conv<<<tg1, 256, 0, stream>>>(eW2, wt + 34L * WMAT);
        transpose_conv<<<tg1, 256, 0, stream>>>(eW3, wt + 35L * WMAT);

        hipMemsetAsync(zero512, 0, 512 * sizeof(float), stream);
        gemm_bt<false><<<dim3(8, 1, 11), 512, 0, stream>>>(
            wt + 33L * WMAT, 0, wt + 22L * WMAT, WMAT, zero512, 0, Mt + WMAT, WMAT);
        hipMemcpyAsync(Mt, wt + 33L * WMAT, WMAT * sizeof(short),
                       hipMemcpyDeviceToDevice, stream);
        hipMemcpyAsync(bB, eb1, 512 * sizeof(float),
                       hipMemcpyDeviceToDevice, stream);
        bias_fold<<<(11 * 512) / 4, 256, 0, stream>>>(tb3, wt + 33L * WMAT, eb1, bB);
    }

    const long SC = CH * 512;
    const dim3 gT((unsigned)(CH / 256 * 4), 1, 11);       // L1,L2: M = CH
    const dim3 gF((unsigned)(CH / 256 * 4), 1, 12);       // fold pass: 12 views
    const dim3 gE((unsigned)(12 * CH / 256 * 4), 1, 1);   // E2,E3: M = 12*CH

    for (int ch = 0; ch < c; ++ch) {
        conv_f32_bf16<<<(unsigned)((SC / 4 + 255) / 256), 256, 0, stream>>>(
            x + (long)ch * SC, S, SC);

        gemm_bt<true ><<<gT, 512, 0, stream>>>(S, 0,  wt + 0L * WMAT,  WMAT, tb1, 512, T + SC, SC);
        gemm_bt<true ><<<gT, 512, 0, stream>>>(T + SC, SC, wt + 11L * WMAT, WMAT, tb2, 512, S + SC, SC);
        gemm_bt<true ><<<gF, 512, 0, stream>>>(S, SC, Mt, WMAT, bB, 512, T, SC);
        gemm_bt<true ><<<gE, 512, 0, stream>>>(T, 0, wt + 34L * WMAT, 0, eb2, 0, S, 0);
        gemm_bt<false><<<gE, 512, 0, stream>>>(S, 0, wt + 35L * WMAT, 0, eb3, 0, T, 0);

        ln_loss<<<(unsigned)(CH / 4), 256, 0, stream>>>(
            T, ln_g, ln_b, (float*)d_out + (long)ch * CH, (int)CH);
    }
}

// Round 18
// 987.385 us; speedup vs baseline: 6.1131x; 1.0380x over previous
//
#include <hip/hip_runtime.h>
#include <hip/hip_bf16.h>
#include <cstdint>

typedef __attribute__((ext_vector_type(8))) short short8;
typedef __attribute__((ext_vector_type(4))) float f32x4;
typedef __attribute__((ext_vector_type(4))) short short4v;

__device__ __forceinline__ float b2f(short s) {
    unsigned u = ((unsigned)(unsigned short)s) << 16;
    return __builtin_bit_cast(float, u);
}
__device__ __forceinline__ short f2b(float f) {
    unsigned u = __builtin_bit_cast(unsigned, f);
    u += 0x7fff + ((u >> 16) & 1);   // RNE
    return (short)(u >> 16);
}

// tanh-form GELU, 8-VALU: gelu = x - x/(1+exp2(x*(c1 + c2*x^2)))
__device__ __forceinline__ float gelu_t(float x) {
    const float c1 = 2.302184829f;     // 2*log2(e)*0.7978845608
    const float c2 = 0.102947246f;     // c1 * 0.044715
    float x2 = x * x;
    float t  = __builtin_fmaf(c2, x2, c1);
    float e  = __builtin_amdgcn_exp2f(x * t);
    return x - __fdividef(x, e + 1.0f);
}

__device__ __forceinline__ void async16(const void* g, void* l) {
    __builtin_amdgcn_global_load_lds(
        (const __attribute__((address_space(1))) unsigned int*)g,
        (__attribute__((address_space(3))) unsigned int*)l, 16, 0, 0);
}

#define VMW(N) asm volatile("s_waitcnt vmcnt(" #N ")" ::: "memory")

// =====================================================================
// 256x256-tile GEMM, K=512, TRUE 8-PHASE schedule (T3+T4+T5):
//  - 8 waves (2M x 4N), per-wave 128x64, acc[8][4]
//  - K-tiles of 64, dbuf (tile&1); each tile = 4 K-SPLIT half-tiles
//    (A_k0,A_k1,B_k0,B_k1; each [256 rows][32 k] = 16 KB, 2 loads/thread)
//  - per phase: 8 ds_read + stage 1 half + vmcnt(8) + bar + lgkm0 +
//    16 MFMA (setprio) + bar.  vmcnt NEVER drains mid-loop.
//  - hazard schedule hand-verified: phase x's wait+barrier protects
//    phase x+1's reads; trailing barrier gates region overwrite.
//  - chunk-swizzle key (row>>1)&3 on 4x16B chunks: 2 lanes/quad = free
// =====================================================================
template<bool GELU>
__global__ __launch_bounds__(512)
void gemm_bt(const short* __restrict__ A, long sA,
             const short* __restrict__ Bt, long sB,
             const float* __restrict__ bias, long sBias,
             short* __restrict__ C, long sC) {
    const int z = blockIdx.z;
    A    += (long)z * sA;
    Bt   += (long)z * sB;
    bias += (long)z * sBias;
    C    += (long)z * sC;

    const int nwg = (int)gridDim.x;
    const int bx  = (int)blockIdx.x;
    int flat = bx;
    if ((nwg & 7) == 0) { const int q = nwg >> 3; flat = (bx & 7) * q + (bx >> 3); }
    const long arow0 = (long)(flat >> 1) * 256;
    const long brow0 = (long)(flat & 1) * 256;

    // 2 bufs x [A_k0|A_k1|B_k0|B_k1] x 8192 shorts = 65536 shorts = 128 KB
    __shared__ alignas(16) short smem[2 * 32768];

    const int tid  = threadIdx.x;
    const int lane = tid & 63;
    const int w    = tid >> 6;             // 0..7
    const int wrow = w >> 2, wcol = w & 3; // 2M x 4N wave grid
    const int lr = lane & 15, hi = lane >> 4;

    f32x4 acc[8][4] = {};

    // stage one half-tile: region = [256][32] shorts, rows 64 B;
    // source chunk pre-swizzled with key (row>>1)&3; dest lane-linear.
    auto stageH = [&](int st, int sks, int sB_) {
        short* reg = smem + (st & 1) * 32768 + (sB_ ? 16384 : 0) + sks * 8192;
        const short* srcb = sB_ ? Bt : A;
        const long r0g = sB_ ? brow0 : arow0;
        const int kc = st * 64 + sks * 32;
#pragma unroll
        for (int jj = 0; jj < 2; ++jj) {
            const int R = w * 32 + jj * 16;
            const int row = R + (lane >> 2);
            const int gc = (lane & 3) ^ ((row >> 1) & 3);
            async16(srcb + (r0g + row) * 512 + kc + gc * 8, reg + R * 32);
        }
    };

    // ---- prologue: t0 all 4 halves + t1 k0 (12 loads); wait t0k0 ----
    stageH(0, 0, 0); stageH(0, 0, 1);
    stageH(0, 1, 0); stageH(0, 1, 1);
    stageH(1, 0, 0); stageH(1, 0, 1);
    VMW(8);
    __builtin_amdgcn_sched_barrier(0);
    __builtin_amdgcn_s_barrier();
    __builtin_amdgcn_sched_barrier(0);

#pragma unroll
    for (int i = 0; i < 4; ++i) {
#pragma unroll
        for (int p = 0; p < 8; ++p) {
            const int tau = 2 * i + (p >> 2);
            const int ks  = (p >> 1) & 1;
            const int mh  = p & 1;
            const short* Ar = smem + (tau & 1) * 32768 + ks * 8192;
            const short* Br = Ar + 16384;
            short8 a[4], b[4];
#pragma unroll
            for (int n = 0; n < 4; ++n) {
                const int row = wcol * 64 + n * 16 + lr;
                b[n] = *(const short8*)&Br[row * 32 + ((hi ^ ((row >> 1) & 3)) << 3)];
            }
#pragma unroll
            for (int j = 0; j < 4; ++j) {
                const int row = wrow * 128 + (mh * 4 + j) * 16 + lr;
                a[j] = *(const short8*)&Ar[row * 32 + ((hi ^ ((row >> 1) & 3)) << 3)];
            }
            // stage schedule: p0,1 -> t(2i+1) k1 A/B; p2,3 -> t(2i+2) k0 A/B;
            //                 p4,5 -> t(2i+2) k1 A/B; p6,7 -> t(2i+3) k0 A/B
            {
                const int st  = (p < 2) ? 2 * i + 1 : (p < 6) ? 2 * i + 2 : 2 * i + 3;
                const int sks = (p < 2) ? 1 : (p < 4) ? 0 : (p < 6) ? 1 : 0;
                const int sB_ = p & 1;
                if (st < 8) stageH(st, sks, sB_);
            }
            if (i < 3) { VMW(8); }
            else if (p < 3) { VMW(8); }
            else if (p < 5) { VMW(4); }
            else { VMW(0); }
            __builtin_amdgcn_sched_barrier(0);
            __builtin_amdgcn_s_barrier();
            __builtin_amdgcn_sched_barrier(0);
            asm volatile("s_waitcnt lgkmcnt(0)" ::: "memory");
            __builtin_amdgcn_sched_barrier(0);
            __builtin_amdgcn_s_setprio(1);
#pragma unroll
            for (int j = 0; j < 4; ++j)
#pragma unroll
                for (int n = 0; n < 4; ++n)
                    acc[mh * 4 + j][n] = __builtin_amdgcn_mfma_f32_16x16x32_bf16(
                        a[j], b[n], acc[mh * 4 + j][n], 0, 0, 0);
            __builtin_amdgcn_s_setprio(0);
            __builtin_amdgcn_s_barrier();
            __builtin_amdgcn_sched_barrier(0);
        }
    }

    // ---- epilogue: 4 half-passes of 32 rows; wave-private E = [32][72] ----
    short* E = smem + w * (32 * 72);
    const int cl = lr, rl = hi * 4;
#pragma unroll
    for (int h = 0; h < 4; ++h) {
#pragma unroll
        for (int n = 0; n < 4; ++n) {
            const int col = (int)brow0 + wcol * 64 + n * 16 + cl;
            const float bs = bias[col];
            const int ecol = n * 16 + cl;
#pragma unroll
            for (int ml = 0; ml < 2; ++ml) {
                const int m = h * 2 + ml;
                float g0 = acc[m][n][0] + bs, g1 = acc[m][n][1] + bs;
                float g2 = acc[m][n][2] + bs, g3 = acc[m][n][3] + bs;
                if (GELU) { g0 = gelu_t(g0); g1 = gelu_t(g1); g2 = gelu_t(g2); g3 = gelu_t(g3); }
                unsigned p01, p23;
                asm("v_cvt_pk_bf16_f32 %0, %1, %2" : "=v"(p01) : "v"(g0), "v"(g1));
                asm("v_cvt_pk_bf16_f32 %0, %1, %2" : "=v"(p23) : "v"(g2), "v"(g3));
                const int r0 = ml * 16 + rl;
                E[(r0 + 0) * 72 + ecol] = (short)(p01 & 0xffff);
                E[(r0 + 1) * 72 + ecol] = (short)(p01 >> 16);
                E[(r0 + 2) * 72 + ecol] = (short)(p23 & 0xffff);
                E[(r0 + 3) * 72 + ecol] = (short)(p23 >> 16);
            }
        }
        // wave-private region: LDS ops in-order within a wave
#pragma unroll
        for (int chunk = 0; chunk < 4; ++chunk) {
            const int rloc = chunk * 8 + (lane >> 3);
            const int c0   = (lane & 7) * 8;
            short8 v = *(const short8*)&E[rloc * 72 + c0];
            *(short8*)&C[(arow0 + wrow * 128 + h * 32 + rloc) * 512
                         + brow0 + wcol * 64 + c0] = v;
        }
    }
}

// ---- transpose+convert: dst[n][k] = bf16(src[k][n]), one 512x512 per blockIdx.z ----
__global__ __launch_bounds__(256)
void transpose_conv(const float* __restrict__ src, short* __restrict__ dst) {
    __shared__ float t[32][33];
    const long moff = (long)blockIdx.z * 512 * 512;
    const float* s = src + moff;
    short* d = dst + moff;
    const int tx = threadIdx.x & 31, ty = threadIdx.x >> 5;
    const int bi = blockIdx.x, bj = blockIdx.y;
#pragma unroll
    for (int j = 0; j < 4; ++j)
        t[ty + j * 8][tx] = s[(long)(bi * 32 + ty + j * 8) * 512 + bj * 32 + tx];
    __syncthreads();
#pragma unroll
    for (int j = 0; j < 4; ++j)
        d[(long)(bj * 32 + ty + j * 8) * 512 + bi * 32 + tx] = f2b(t[tx][ty + j * 8]);
}

// ---- f32 -> bf16 elementwise ----
__global__ __launch_bounds__(256)
void conv_f32_bf16(const float* __restrict__ src, short* __restrict__ dst, long n) {
    long i = ((long)blockIdx.x * 256 + threadIdx.x) * 4;
    if (i >= n) return;
    float4 f = *(const float4*)&src[i];
    short4v o;
    o[0] = f2b(f.x); o[1] = f2b(f.y); o[2] = f2b(f.z); o[3] = f2b(f.w);
    *(short4v*)&dst[i] = o;
}

// ---- bias fold: bB[(k+1)*512+n] = dot(tb3_k, eW1[:,n]) + eb1[n] ----
__global__ __launch_bounds__(256)
void bias_fold(const float* __restrict__ tb3, const short* __restrict__ wtE1,
               const float* __restrict__ eb1, float* __restrict__ bB) {
    const int wid = threadIdx.x >> 6, lane = threadIdx.x & 63;
    const int idx = blockIdx.x * 4 + wid;        // 0 .. 11*512-1
    const int k = idx >> 9, n = idx & 511;
    short8 wv = *(const short8*)&wtE1[(long)n * 512 + lane * 8];
    const float* tb = tb3 + (long)k * 512 + lane * 8;
    float s = 0.f;
#pragma unroll
    for (int j = 0; j < 8; ++j) s += b2f(wv[j]) * tb[j];
#pragma unroll
    for (int o = 1; o < 64; o <<= 1) s += __shfl_xor(s, o, 64);
    if (lane == 0) bB[(long)(k + 1) * 512 + n] = s + eb1[n];
}

// ---- fused LN + L2-normalize + MFMA Gram + logsumexp loss (r12-proven) ----
__global__ __launch_bounds__(256)
void ln_loss(const short* __restrict__ H, const float* __restrict__ g,
             const float* __restrict__ bta, float* __restrict__ out, int CH) {
    __shared__ alignas(16) short Z[4][16 * 520];
    const int wid = threadIdx.x >> 6, lane = threadIdx.x & 63;
    const long b = (long)blockIdx.x * 4 + wid;
    short* Zw = &Z[wid][0];

#pragma unroll
    for (int r = 12; r < 16; ++r)
        *(short8*)&Zw[r * 520 + lane * 8] = (short8){0, 0, 0, 0, 0, 0, 0, 0};

    for (int s = 0; s < 12; ++s) {
        short8 t = *(const short8*)&H[((long)s * CH + b) * 512 + lane * 8];
        float v[8];
        float sum = 0.f, ss = 0.f;
#pragma unroll
        for (int j = 0; j < 8; ++j) { v[j] = b2f(t[j]); sum += v[j]; ss += v[j] * v[j]; }
#pragma unroll
        for (int o = 1; o < 64; o <<= 1) { sum += __shfl_xor(sum, o, 64); ss += __shfl_xor(ss, o, 64); }
        const float mu = sum * (1.f / 512.f);
        const float rs = rsqrtf(ss * (1.f / 512.f) - mu * mu + 1e-5f);
        float y[8]; float nsq = 0.f;
#pragma unroll
        for (int j = 0; j < 8; ++j) {
            const int col = lane * 8 + j;
            y[j] = (v[j] - mu) * rs * g[col] + bta[col];
            nsq += y[j] * y[j];
        }
#pragma unroll
        for (int o = 1; o < 64; o <<= 1) nsq += __shfl_xor(nsq, o, 64);
        const float inv = 1.f / fmaxf(sqrtf(nsq), 1e-8f);
        short8 o8;
#pragma unroll
        for (int j = 0; j < 8; ++j) o8[j] = f2b(y[j] * inv);
        *(short8*)&Zw[s * 520 + lane * 8] = o8;
    }

    f32x4 acc = {0.f, 0.f, 0.f, 0.f};
    const int lr = lane & 15, hi = lane >> 4;
#pragma unroll
    for (int st = 0; st < 16; ++st) {
        short8 a = *(const short8*)&Zw[lr * 520 + st * 32 + hi * 8];
        acc = __builtin_amdgcn_mfma_f32_16x16x32_bf16(a, a, acc, 0, 0, 0);
    }
    const int col = lr;
    float lmax = -3.0e38f;
    bool valid[4];
#pragma unroll
    for (int i = 0; i < 4; ++i) {
        const int row = hi * 4 + i;
        valid[i] = (row < 12) && (row != col);
        if (valid[i]) lmax = fmaxf(lmax, acc[i]);
    }
    lmax = fmaxf(lmax, __shfl_xor(lmax, 16, 64));
    lmax = fmaxf(lmax, __shfl_xor(lmax, 32, 64));
    float esum = 0.f;
#pragma unroll
    for (int i = 0; i < 4; ++i)
        if (valid[i]) esum += __builtin_amdgcn_exp2f((acc[i] - lmax) * 1.44269504f);
    esum += __shfl_xor(esum, 16, 64);
    esum += __shfl_xor(esum, 32, 64);
    float contrib = 0.f;
    if (hi == 0 && col >= 1 && col <= 11) {
        const float logden = lmax + __builtin_amdgcn_logf(esum) * 0.6931471806f;
        contrib = acc[0] - logden;
    }
#pragma unroll
    for (int o = 1; o < 16; o <<= 1) contrib += __shfl_xor(contrib, o, 64);
    if (lane == 0) out[b] = -contrib;
}

// ---------------- host ----------------
extern "C" void kernel_launch(void* const* d_in, const int* in_sizes, int n_in,
                              void* d_out, int out_size, void* d_ws, size_t ws_size,
                              hipStream_t stream) {
    const float* x    = (const float*)d_in[0];
    const float* tW1  = (const float*)d_in[1];
    const float* tb1  = (const float*)d_in[2];
    const float* tW2  = (const float*)d_in[3];
    const float* tb2  = (const float*)d_in[4];
    const float* tW3  = (const float*)d_in[5];
    const float* tb3  = (const float*)d_in[6];
    const float* eW1  = (const float*)d_in[7];
    const float* eb1  = (const float*)d_in[8];
    const float* eW2  = (const float*)d_in[9];
    const float* eb2  = (const float*)d_in[10];
    const float* eW3  = (const float*)d_in[11];
    const float* eb3  = (const float*)d_in[12];
    const float* ln_g = (const float*)d_in[13];
    const float* ln_b = (const float*)d_in[14];

    const int  B    = in_sizes[0] / 512;   // 16384
    const long WMAT = 512L * 512L;

    int  c  = 1;
    long CH = B;
    for (;;) {
        CH = (long)B / c;
        size_t need = (size_t)48 * WMAT * 2 + (512 + 12 * 512) * 4
                    + (size_t)24 * CH * 512 * 2 + 8192;
        if (need <= ws_size || CH <= 256) break;
        c <<= 1;
    }
    const long SLAB = 12L * CH * 512;

    short* wt   = (short*)d_ws;             // 0..21: tW1^T,tW2^T; 22..32: tW3 (orig); 33..35: eW^T
    short* Mt   = wt + 36L * WMAT;          // slot0 = eW1^T, 1..11 = (tW3_k·eW1)^T
    float* zero512 = (float*)(Mt + 12L * WMAT);
    float* bB   = zero512 + 512;            // 12x512 folded biases
    short* S    = (short*)(bB + 12 * 512);  // slab S [12, CH, 512]
    short* T    = S + SLAB;                 // slab T [12, CH, 512]

    // --- weight prep (once per launch) ---
    {
        dim3 tgK(16, 16, 11), tg1(16, 16, 1);
        transpose_conv<<<tgK, 256, 0, stream>>>(tW1, wt + 0L * WMAT);
        transpose_conv<<<tgK, 256, 0, stream>>>(tW2, wt + 11L * WMAT);
        conv_f32_bf16<<<(unsigned)((11 * WMAT / 4 + 255) / 256), 256, 0, stream>>>(
            tW3, wt + 22L * WMAT, 11 * WMAT);
        transpose_conv<<<tg1, 256, 0, stream>>>(eW1, wt + 33L * WMAT);
        transpose_conv<<<tg1, 256, 0, stream>>>(eW2, wt + 34L * WMAT);
        transpose_conv<<<tg1, 256, 0, stream>>>(eW3, wt + 35L * WMAT);

        hipMemsetAsync(zero512, 0, 512 * sizeof(float), stream);
        gemm_bt<false><<<dim3(4, 1, 11), 512, 0, stream>>>(
            wt + 33L * WMAT, 0, wt + 22L * WMAT, WMAT, zero512, 0, Mt + WMAT, WMAT);
        hipMemcpyAsync(Mt, wt + 33L * WMAT, WMAT * sizeof(short),
                       hipMemcpyDeviceToDevice, stream);
        hipMemcpyAsync(bB, eb1, 512 * sizeof(float),
                       hipMemcpyDeviceToDevice, stream);
        bias_fold<<<(11 * 512) / 4, 256, 0, stream>>>(tb3, wt + 33L * WMAT, eb1, bB);
    }

    const long SC = CH * 512;
    const dim3 gT((unsigned)(CH / 256 * 2), 1, 11);       // L1,L2: M = CH
    const dim3 gF((unsigned)(CH / 256 * 2), 1, 12);       // fold pass: 12 views
    const dim3 gE((unsigned)(12 * CH / 256 * 2), 1, 1);   // E2,E3: M = 12*CH

    for (int ch = 0; ch < c; ++ch) {
        conv_f32_bf16<<<(unsigned)((SC / 4 + 255) / 256), 256, 0, stream>>>(
            x + (long)ch * SC, S, SC);

        gemm_bt<true ><<<gT, 512, 0, stream>>>(S, 0,  wt + 0L * WMAT,  WMAT, tb1, 512, T + SC, SC);
        gemm_bt<true ><<<gT, 512, 0, stream>>>(T + SC, SC, wt + 11L * WMAT, WMAT, tb2, 512, S + SC, SC);
        gemm_bt<true ><<<gF, 512, 0, stream>>>(S, SC, Mt, WMAT, bB, 512, T, SC);
        gemm_bt<true ><<<gE, 512, 0, stream>>>(T, 0, wt + 34L * WMAT, 0, eb2, 0, S, 0);
        gemm_bt<false><<<gE, 512, 0, stream>>>(S, 0, wt + 35L * WMAT, 0, eb3, 0, T, 0);

        ln_loss<<<(unsigned)(CH / 4), 256, 0, stream>>>(
            T, ln_g, ln_b, (float*)d_out + (long)ch * CH, (int)CH);
    }
}

// Round 19
// 976.680 us; speedup vs baseline: 6.1801x; 1.0110x over previous
//
#include <hip/hip_runtime.h>
#include <hip/hip_bf16.h>
#include <cstdint>

typedef __attribute__((ext_vector_type(8))) short short8;
typedef __attribute__((ext_vector_type(4))) float f32x4;
typedef __attribute__((ext_vector_type(4))) short short4v;

__device__ __forceinline__ float b2f(short s) {
    unsigned u = ((unsigned)(unsigned short)s) << 16;
    return __builtin_bit_cast(float, u);
}
__device__ __forceinline__ short f2b(float f) {
    unsigned u = __builtin_bit_cast(unsigned, f);
    u += 0x7fff + ((u >> 16) & 1);   // RNE
    return (short)(u >> 16);
}

// tanh-form GELU, 8-VALU: gelu = x - x/(1+exp2(x*(c1 + c2*x^2)))
__device__ __forceinline__ float gelu_t(float x) {
    const float c1 = 2.302184829f;     // 2*log2(e)*0.7978845608
    const float c2 = 0.102947246f;     // c1 * 0.044715
    float x2 = x * x;
    float t  = __builtin_fmaf(c2, x2, c1);
    float e  = __builtin_amdgcn_exp2f(x * t);
    return x - __fdividef(x, e + 1.0f);
}

__device__ __forceinline__ void async16(const void* g, void* l) {
    __builtin_amdgcn_global_load_lds(
        (const __attribute__((address_space(1))) unsigned int*)g,
        (__attribute__((address_space(3))) unsigned int*)l, 16, 0, 0);
}

#define VMW(N) asm volatile("s_waitcnt vmcnt(" #N ")" ::: "memory")

// =====================================================================
// 256x256-tile GEMM, K=512, 8-phase counted-vmcnt schedule, r19:
//  - waits ONLY at even phases (vmcnt(8); tail 8,8,4,0) — odd phases
//    reuse the already-waited half (no drain)
//  - ONE raw barrier per phase (even-lead / odd-trail); overwrite
//    gating re-verified for the r18 stagger
//  - no explicit lgkmcnt, minimal sched_barriers (compiler schedules
//    LDS->MFMA; m141 lesson)
// =====================================================================
template<bool GELU>
__global__ __launch_bounds__(512)
void gemm_bt(const short* __restrict__ A, long sA,
             const short* __restrict__ Bt, long sB,
             const float* __restrict__ bias, long sBias,
             short* __restrict__ C, long sC) {
    const int z = blockIdx.z;
    A    += (long)z * sA;
    Bt   += (long)z * sB;
    bias += (long)z * sBias;
    C    += (long)z * sC;

    const int nwg = (int)gridDim.x;
    const int bx  = (int)blockIdx.x;
    int flat = bx;
    if ((nwg & 7) == 0) { const int q = nwg >> 3; flat = (bx & 7) * q + (bx >> 3); }
    const long arow0 = (long)(flat >> 1) * 256;
    const long brow0 = (long)(flat & 1) * 256;

    // 2 bufs x [A_k0|A_k1|B_k0|B_k1] x 8192 shorts = 128 KB
    __shared__ alignas(16) short smem[2 * 32768];

    const int tid  = threadIdx.x;
    const int lane = tid & 63;
    const int w    = tid >> 6;             // 0..7
    const int wrow = w >> 2, wcol = w & 3; // 2M x 4N wave grid
    const int lr = lane & 15, hi = lane >> 4;

    f32x4 acc[8][4] = {};

    // stage one half-tile [256 rows][32 k]; rows 64 B; key (row>>1)&3
    auto stageH = [&](int st, int sks, int sB_) {
        short* reg = smem + (st & 1) * 32768 + (sB_ ? 16384 : 0) + sks * 8192;
        const short* srcb = sB_ ? Bt : A;
        const long r0g = sB_ ? brow0 : arow0;
        const int kc = st * 64 + sks * 32;
#pragma unroll
        for (int jj = 0; jj < 2; ++jj) {
            const int R = w * 32 + jj * 16;
            const int row = R + (lane >> 2);
            const int gc = (lane & 3) ^ ((row >> 1) & 3);
            async16(srcb + (r0g + row) * 512 + kc + gc * 8, reg + R * 32);
        }
    };

    // ---- prologue: t0 all 4 halves + t1 k0 (12 loads) ----
    stageH(0, 0, 0); stageH(0, 0, 1);
    stageH(0, 1, 0); stageH(0, 1, 1);
    stageH(1, 0, 0); stageH(1, 0, 1);

#pragma unroll
    for (int i = 0; i < 4; ++i) {
#pragma unroll
        for (int p = 0; p < 8; ++p) {
            const int tau = 2 * i + (p >> 2);
            const int ks  = (p >> 1) & 1;
            const int mh  = p & 1;
            const short* Ar = smem + (tau & 1) * 32768 + ks * 8192;
            const short* Br = Ar + 16384;

            if (mh == 0) {
                // even phase: wait for half (tau,ks), publish, then read
                if (i < 3)       { VMW(8); }
                else if (p == 0) { VMW(8); }
                else if (p == 2) { VMW(8); }
                else if (p == 4) { VMW(4); }
                else             { VMW(0); }
                __builtin_amdgcn_s_barrier();
                __builtin_amdgcn_sched_barrier(0);
            }

            short8 a[4], b[4];
#pragma unroll
            for (int n = 0; n < 4; ++n) {
                const int row = wcol * 64 + n * 16 + lr;
                b[n] = *(const short8*)&Br[row * 32 + ((hi ^ ((row >> 1) & 3)) << 3)];
            }
#pragma unroll
            for (int j = 0; j < 4; ++j) {
                const int row = wrow * 128 + (mh * 4 + j) * 16 + lr;
                a[j] = *(const short8*)&Ar[row * 32 + ((hi ^ ((row >> 1) & 3)) << 3)];
            }

            // stage schedule (r18-verified stagger)
            {
                const int st  = (p < 2) ? 2 * i + 1 : (p < 6) ? 2 * i + 2 : 2 * i + 3;
                const int sks = (p < 2) ? 1 : (p < 4) ? 0 : (p < 6) ? 1 : 0;
                const int sB_ = p & 1;
                if (st < 8) stageH(st, sks, sB_);
            }

            __builtin_amdgcn_s_setprio(1);
#pragma unroll
            for (int j = 0; j < 4; ++j)
#pragma unroll
                for (int n = 0; n < 4; ++n)
                    acc[mh * 4 + j][n] = __builtin_amdgcn_mfma_f32_16x16x32_bf16(
                        a[j], b[n], acc[mh * 4 + j][n], 0, 0, 0);
            __builtin_amdgcn_s_setprio(0);

            if (mh == 1) {
                // odd phase: trailing barrier gates next phases' staging
                __builtin_amdgcn_sched_barrier(0);
                __builtin_amdgcn_s_barrier();
            }
        }
    }

    // ---- epilogue: 4 half-passes of 32 rows; wave-private E = [32][72] ----
    short* E = smem + w * (32 * 72);
    const int cl = lr, rl = hi * 4;
#pragma unroll
    for (int h = 0; h < 4; ++h) {
#pragma unroll
        for (int n = 0; n < 4; ++n) {
            const int col = (int)brow0 + wcol * 64 + n * 16 + cl;
            const float bs = bias[col];
            const int ecol = n * 16 + cl;
#pragma unroll
            for (int ml = 0; ml < 2; ++ml) {
                const int m = h * 2 + ml;
                float g0 = acc[m][n][0] + bs, g1 = acc[m][n][1] + bs;
                float g2 = acc[m][n][2] + bs, g3 = acc[m][n][3] + bs;
                if (GELU) { g0 = gelu_t(g0); g1 = gelu_t(g1); g2 = gelu_t(g2); g3 = gelu_t(g3); }
                unsigned p01, p23;
                asm("v_cvt_pk_bf16_f32 %0, %1, %2" : "=v"(p01) : "v"(g0), "v"(g1));
                asm("v_cvt_pk_bf16_f32 %0, %1, %2" : "=v"(p23) : "v"(g2), "v"(g3));
                const int r0 = ml * 16 + rl;
                E[(r0 + 0) * 72 + ecol] = (short)(p01 & 0xffff);
                E[(r0 + 1) * 72 + ecol] = (short)(p01 >> 16);
                E[(r0 + 2) * 72 + ecol] = (short)(p23 & 0xffff);
                E[(r0 + 3) * 72 + ecol] = (short)(p23 >> 16);
            }
        }
        // wave-private region: LDS ops in-order within a wave
#pragma unroll
        for (int chunk = 0; chunk < 4; ++chunk) {
            const int rloc = chunk * 8 + (lane >> 3);
            const int c0   = (lane & 7) * 8;
            short8 v = *(const short8*)&E[rloc * 72 + c0];
            *(short8*)&C[(arow0 + wrow * 128 + h * 32 + rloc) * 512
                         + brow0 + wcol * 64 + c0] = v;
        }
    }
}

// ---- transpose+convert: dst[n][k] = bf16(src[k][n]), one 512x512 per blockIdx.z ----
__global__ __launch_bounds__(256)
void transpose_conv(const float* __restrict__ src, short* __restrict__ dst) {
    __shared__ float t[32][33];
    const long moff = (long)blockIdx.z * 512 * 512;
    const float* s = src + moff;
    short* d = dst + moff;
    const int tx = threadIdx.x & 31, ty = threadIdx.x >> 5;
    const int bi = blockIdx.x, bj = blockIdx.y;
#pragma unroll
    for (int j = 0; j < 4; ++j)
        t[ty + j * 8][tx] = s[(long)(bi * 32 + ty + j * 8) * 512 + bj * 32 + tx];
    __syncthreads();
#pragma unroll
    for (int j = 0; j < 4; ++j)
        d[(long)(bj * 32 + ty + j * 8) * 512 + bi * 32 + tx] = f2b(t[tx][ty + j * 8]);
}

// ---- f32 -> bf16 elementwise ----
__global__ __launch_bounds__(256)
void conv_f32_bf16(const float* __restrict__ src, short* __restrict__ dst, long n) {
    long i = ((long)blockIdx.x * 256 + threadIdx.x) * 4;
    if (i >= n) return;
    float4 f = *(const float4*)&src[i];
    short4v o;
    o[0] = f2b(f.x); o[1] = f2b(f.y); o[2] = f2b(f.z); o[3] = f2b(f.w);
    *(short4v*)&dst[i] = o;
}

// ---- bias fold: bB[(k+1)*512+n] = dot(tb3_k, eW1[:,n]) + eb1[n] ----
__global__ __launch_bounds__(256)
void bias_fold(const float* __restrict__ tb3, const short* __restrict__ wtE1,
               const float* __restrict__ eb1, float* __restrict__ bB) {
    const int wid = threadIdx.x >> 6, lane = threadIdx.x & 63;
    const int idx = blockIdx.x * 4 + wid;        // 0 .. 11*512-1
    const int k = idx >> 9, n = idx & 511;
    short8 wv = *(const short8*)&wtE1[(long)n * 512 + lane * 8];
    const float* tb = tb3 + (long)k * 512 + lane * 8;
    float s = 0.f;
#pragma unroll
    for (int j = 0; j < 8; ++j) s += b2f(wv[j]) * tb[j];
#pragma unroll
    for (int o = 1; o < 64; o <<= 1) s += __shfl_xor(s, o, 64);
    if (lane == 0) bB[(long)(k + 1) * 512 + n] = s + eb1[n];
}

// ---- fused LN + L2-normalize + MFMA Gram + logsumexp loss (r12-proven) ----
__global__ __launch_bounds__(256)
void ln_loss(const short* __restrict__ H, const float* __restrict__ g,
             const float* __restrict__ bta, float* __restrict__ out, int CH) {
    __shared__ alignas(16) short Z[4][16 * 520];
    const int wid = threadIdx.x >> 6, lane = threadIdx.x & 63;
    const long b = (long)blockIdx.x * 4 + wid;
    short* Zw = &Z[wid][0];

#pragma unroll
    for (int r = 12; r < 16; ++r)
        *(short8*)&Zw[r * 520 + lane * 8] = (short8){0, 0, 0, 0, 0, 0, 0, 0};

    for (int s = 0; s < 12; ++s) {
        short8 t = *(const short8*)&H[((long)s * CH + b) * 512 + lane * 8];
        float v[8];
        float sum = 0.f, ss = 0.f;
#pragma unroll
        for (int j = 0; j < 8; ++j) { v[j] = b2f(t[j]); sum += v[j]; ss += v[j] * v[j]; }
#pragma unroll
        for (int o = 1; o < 64; o <<= 1) { sum += __shfl_xor(sum, o, 64); ss += __shfl_xor(ss, o, 64); }
        const float mu = sum * (1.f / 512.f);
        const float rs = rsqrtf(ss * (1.f / 512.f) - mu * mu + 1e-5f);
        float y[8]; float nsq = 0.f;
#pragma unroll
        for (int j = 0; j < 8; ++j) {
            const int col = lane * 8 + j;
            y[j] = (v[j] - mu) * rs * g[col] + bta[col];
            nsq += y[j] * y[j];
        }
#pragma unroll
        for (int o = 1; o < 64; o <<= 1) nsq += __shfl_xor(nsq, o, 64);
        const float inv = 1.f / fmaxf(sqrtf(nsq), 1e-8f);
        short8 o8;
#pragma unroll
        for (int j = 0; j < 8; ++j) o8[j] = f2b(y[j] * inv);
        *(short8*)&Zw[s * 520 + lane * 8] = o8;
    }

    f32x4 acc = {0.f, 0.f, 0.f, 0.f};
    const int lr = lane & 15, hi = lane >> 4;
#pragma unroll
    for (int st = 0; st < 16; ++st) {
        short8 a = *(const short8*)&Zw[lr * 520 + st * 32 + hi * 8];
        acc = __builtin_amdgcn_mfma_f32_16x16x32_bf16(a, a, acc, 0, 0, 0);
    }
    const int col = lr;
    float lmax = -3.0e38f;
    bool valid[4];
#pragma unroll
    for (int i = 0; i < 4; ++i) {
        const int row = hi * 4 + i;
        valid[i] = (row < 12) && (row != col);
        if (valid[i]) lmax = fmaxf(lmax, acc[i]);
    }
    lmax = fmaxf(lmax, __shfl_xor(lmax, 16, 64));
    lmax = fmaxf(lmax, __shfl_xor(lmax, 32, 64));
    float esum = 0.f;
#pragma unroll
    for (int i = 0; i < 4; ++i)
        if (valid[i]) esum += __builtin_amdgcn_exp2f((acc[i] - lmax) * 1.44269504f);
    esum += __shfl_xor(esum, 16, 64);
    esum += __shfl_xor(esum, 32, 64);
    float contrib = 0.f;
    if (hi == 0 && col >= 1 && col <= 11) {
        const float logden = lmax + __builtin_amdgcn_logf(esum) * 0.6931471806f;
        contrib = acc[0] - logden;
    }
#pragma unroll
    for (int o = 1; o < 16; o <<= 1) contrib += __shfl_xor(contrib, o, 64);
    if (lane == 0) out[b] = -contrib;
}

// ---------------- host ----------------
extern "C" void kernel_launch(void* const* d_in, const int* in_sizes, int n_in,
                              void* d_out, int out_size, void* d_ws, size_t ws_size,
                              hipStream_t stream) {
    const float* x    = (const float*)d_in[0];
    const float* tW1  = (const float*)d_in[1];
    const float* tb1  = (const float*)d_in[2];
    const float* tW2  = (const float*)d_in[3];
    const float* tb2  = (const float*)d_in[4];
    const float* tW3  = (const float*)d_in[5];
    const float* tb3  = (const float*)d_in[6];
    const float* eW1  = (const float*)d_in[7];
    const float* eb1  = (const float*)d_in[8];
    const float* eW2  = (const float*)d_in[9];
    const float* eb2  = (const float*)d_in[10];
    const float* eW3  = (const float*)d_in[11];
    const float* eb3  = (const float*)d_in[12];
    const float* ln_g = (const float*)d_in[13];
    const float* ln_b = (const float*)d_in[14];

    const int  B    = in_sizes[0] / 512;   // 16384
    const long WMAT = 512L * 512L;

    int  c  = 1;
    long CH = B;
    for (;;) {
        CH = (long)B / c;
        size_t need = (size_t)48 * WMAT * 2 + (512 + 12 * 512) * 4
                    + (size_t)24 * CH * 512 * 2 + 8192;
        if (need <= ws_size || CH <= 256) break;
        c <<= 1;
    }
    const long SLAB = 12L * CH * 512;

    short* wt   = (short*)d_ws;             // 0..21: tW1^T,tW2^T; 22..32: tW3 (orig); 33..35: eW^T
    short* Mt   = wt + 36L * WMAT;          // slot0 = eW1^T, 1..11 = (tW3_k·eW1)^T
    float* zero512 = (float*)(Mt + 12L * WMAT);
    float* bB   = zero512 + 512;            // 12x512 folded biases
    short* S    = (short*)(bB + 12 * 512);  // slab S [12, CH, 512]
    short* T    = S + SLAB;                 // slab T [12, CH, 512]

    // --- weight prep (once per launch) ---
    {
        dim3 tgK(16, 16, 11), tg1(16, 16, 1);
        transpose_conv<<<tgK, 256, 0, stream>>>(tW1, wt + 0L * WMAT);
        transpose_conv<<<tgK, 256, 0, stream>>>(tW2, wt + 11L * WMAT);
        conv_f32_bf16<<<(unsigned)((11 * WMAT / 4 + 255) / 256), 256, 0, stream>>>(
            tW3, wt + 22L * WMAT, 11 * WMAT);
        transpose_conv<<<tg1, 256, 0, stream>>>(eW1, wt + 33L * WMAT);
        transpose_conv<<<tg1, 256, 0, stream>>>(eW2, wt + 34L * WMAT);
        transpose_conv<<<tg1, 256, 0, stream>>>(eW3, wt + 35L * WMAT);

        hipMemsetAsync(zero512, 0, 512 * sizeof(float), stream);
        gemm_bt<false><<<dim3(4, 1, 11), 512, 0, stream>>>(
            wt + 33L * WMAT, 0, wt + 22L * WMAT, WMAT, zero512, 0, Mt + WMAT, WMAT);
        hipMemcpyAsync(Mt, wt + 33L * WMAT, WMAT * sizeof(short),
                       hipMemcpyDeviceToDevice, stream);
        hipMemcpyAsync(bB, eb1, 512 * sizeof(float),
                       hipMemcpyDeviceToDevice, stream);
        bias_fold<<<(11 * 512) / 4, 256, 0, stream>>>(tb3, wt + 33L * WMAT, eb1, bB);
    }

    const long SC = CH * 512;
    const dim3 gT((unsigned)(CH / 256 * 2), 1, 11);       // L1,L2: M = CH
    const dim3 gF((unsigned)(CH / 256 * 2), 1, 12);       // fold pass: 12 views
    const dim3 gE((unsigned)(12 * CH / 256 * 2), 1, 1);   // E2,E3: M = 12*CH

    for (int ch = 0; ch < c; ++ch) {
        conv_f32_bf16<<<(unsigned)((SC / 4 + 255) / 256), 256, 0, stream>>>(
            x + (long)ch * SC, S, SC);

        gemm_bt<true ><<<gT, 512, 0, stream>>>(S, 0,  wt + 0L * WMAT,  WMAT, tb1, 512, T + SC, SC);
        gemm_bt<true ><<<gT, 512, 0, stream>>>(T + SC, SC, wt + 11L * WMAT, WMAT, tb2, 512, S + SC, SC);
        gemm_bt<true ><<<gF, 512, 0, stream>>>(S, SC, Mt, WMAT, bB, 512, T, SC);
        gemm_bt<true ><<<gE, 512, 0, stream>>>(T, 0, wt + 34L * WMAT, 0, eb2, 0, S, 0);
        gemm_bt<false><<<gE, 512, 0, stream>>>(S, 0, wt + 35L * WMAT, 0, eb3, 0, T, 0);

        ln_loss<<<(unsigned)(CH / 4), 256, 0, stream>>>(
            T, ln_g, ln_b, (float*)d_out + (long)ch * CH, (int)CH);
    }
}

// Round 20
// 962.890 us; speedup vs baseline: 6.2686x; 1.0143x over previous
//
#include <hip/hip_runtime.h>
#include <hip/hip_bf16.h>
#include <cstdint>

typedef __attribute__((ext_vector_type(8))) short short8;
typedef __attribute__((ext_vector_type(4))) float f32x4;
typedef __attribute__((ext_vector_type(4))) short short4v;

__device__ __forceinline__ float b2f(short s) {
    unsigned u = ((unsigned)(unsigned short)s) << 16;
    return __builtin_bit_cast(float, u);
}
__device__ __forceinline__ short f2b(float f) {
    unsigned u = __builtin_bit_cast(unsigned, f);
    u += 0x7fff + ((u >> 16) & 1);   // RNE
    return (short)(u >> 16);
}

// tanh-form GELU, 8-VALU: gelu = x - x/(1+exp2(x*(c1 + c2*x^2)))
__device__ __forceinline__ float gelu_t(float x) {
    const float c1 = 2.302184829f;     // 2*log2(e)*0.7978845608
    const float c2 = 0.102947246f;     // c1 * 0.044715
    float x2 = x * x;
    float t  = __builtin_fmaf(c2, x2, c1);
    float e  = __builtin_amdgcn_exp2f(x * t);
    return x - __fdividef(x, e + 1.0f);
}

__device__ __forceinline__ void async16(const void* g, void* l) {
    __builtin_amdgcn_global_load_lds(
        (const __attribute__((address_space(1))) unsigned int*)g,
        (__attribute__((address_space(3))) unsigned int*)l, 16, 0, 0);
}

#define VMW(N) asm volatile("s_waitcnt vmcnt(" #N ")" ::: "memory")

// =====================================================================
// 256x256-tile GEMM, K=512, 8-phase counted-vmcnt schedule, r20:
//  - r19 discipline (even-phase waits, one barrier/phase)
//  - NEW: B-fragment REGISTER REUSE across the (mh=0,1) phase pair —
//    b[4] loaded only at even phases. Cuts LDS reads 128->96 KB per
//    k32 (the measured binding resource: ~70% of phase time was
//    LDS-read at 85 B/cyc).
// =====================================================================
template<bool GELU>
__global__ __launch_bounds__(512)
void gemm_bt(const short* __restrict__ A, long sA,
             const short* __restrict__ Bt, long sB,
             const float* __restrict__ bias, long sBias,
             short* __restrict__ C, long sC) {
    const int z = blockIdx.z;
    A    += (long)z * sA;
    Bt   += (long)z * sB;
    bias += (long)z * sBias;
    C    += (long)z * sC;

    const int nwg = (int)gridDim.x;
    const int bx  = (int)blockIdx.x;
    int flat = bx;
    if ((nwg & 7) == 0) { const int q = nwg >> 3; flat = (bx & 7) * q + (bx >> 3); }
    const long arow0 = (long)(flat >> 1) * 256;
    const long brow0 = (long)(flat & 1) * 256;

    // 2 bufs x [A_k0|A_k1|B_k0|B_k1] x 8192 shorts = 128 KB
    __shared__ alignas(16) short smem[2 * 32768];

    const int tid  = threadIdx.x;
    const int lane = tid & 63;
    const int w    = tid >> 6;             // 0..7
    const int wrow = w >> 2, wcol = w & 3; // 2M x 4N wave grid
    const int lr = lane & 15, hi = lane >> 4;

    f32x4 acc[8][4] = {};

    // stage one half-tile [256 rows][32 k]; rows 64 B; key (row>>1)&3
    auto stageH = [&](int st, int sks, int sB_) {
        short* reg = smem + (st & 1) * 32768 + (sB_ ? 16384 : 0) + sks * 8192;
        const short* srcb = sB_ ? Bt : A;
        const long r0g = sB_ ? brow0 : arow0;
        const int kc = st * 64 + sks * 32;
#pragma unroll
        for (int jj = 0; jj < 2; ++jj) {
            const int R = w * 32 + jj * 16;
            const int row = R + (lane >> 2);
            const int gc = (lane & 3) ^ ((row >> 1) & 3);
            async16(srcb + (r0g + row) * 512 + kc + gc * 8, reg + R * 32);
        }
    };

    // ---- prologue: t0 all 4 halves + t1 k0 (12 loads) ----
    stageH(0, 0, 0); stageH(0, 0, 1);
    stageH(0, 1, 0); stageH(0, 1, 1);
    stageH(1, 0, 0); stageH(1, 0, 1);

    short8 b[4];   // lives across the (mh=0,1) phase pair

#pragma unroll
    for (int i = 0; i < 4; ++i) {
#pragma unroll
        for (int p = 0; p < 8; ++p) {
            const int tau = 2 * i + (p >> 2);
            const int ks  = (p >> 1) & 1;
            const int mh  = p & 1;
            const short* Ar = smem + (tau & 1) * 32768 + ks * 8192;
            const short* Br = Ar + 16384;

            if (mh == 0) {
                // even phase: wait for half (tau,ks), publish, then read
                if (i < 3)       { VMW(8); }
                else if (p == 0) { VMW(8); }
                else if (p == 2) { VMW(8); }
                else if (p == 4) { VMW(4); }
                else             { VMW(0); }
                __builtin_amdgcn_s_barrier();
                __builtin_amdgcn_sched_barrier(0);
                // B fragments: once per pair (register reuse at mh==1)
#pragma unroll
                for (int n = 0; n < 4; ++n) {
                    const int row = wcol * 64 + n * 16 + lr;
                    b[n] = *(const short8*)&Br[row * 32 + ((hi ^ ((row >> 1) & 3)) << 3)];
                }
            }

            short8 a[4];
#pragma unroll
            for (int j = 0; j < 4; ++j) {
                const int row = wrow * 128 + (mh * 4 + j) * 16 + lr;
                a[j] = *(const short8*)&Ar[row * 32 + ((hi ^ ((row >> 1) & 3)) << 3)];
            }

            // stage schedule (r18-verified stagger)
            {
                const int st  = (p < 2) ? 2 * i + 1 : (p < 6) ? 2 * i + 2 : 2 * i + 3;
                const int sks = (p < 2) ? 1 : (p < 4) ? 0 : (p < 6) ? 1 : 0;
                const int sB_ = p & 1;
                if (st < 8) stageH(st, sks, sB_);
            }

            __builtin_amdgcn_s_setprio(1);
#pragma unroll
            for (int j = 0; j < 4; ++j)
#pragma unroll
                for (int n = 0; n < 4; ++n)
                    acc[mh * 4 + j][n] = __builtin_amdgcn_mfma_f32_16x16x32_bf16(
                        a[j], b[n], acc[mh * 4 + j][n], 0, 0, 0);
            __builtin_amdgcn_s_setprio(0);

            if (mh == 1) {
                // odd phase: trailing barrier gates next phases' staging
                __builtin_amdgcn_sched_barrier(0);
                __builtin_amdgcn_s_barrier();
            }
        }
    }

    // ---- epilogue: 4 half-passes of 32 rows; wave-private E = [32][72] ----
    short* E = smem + w * (32 * 72);
    const int cl = lr, rl = hi * 4;
#pragma unroll
    for (int h = 0; h < 4; ++h) {
#pragma unroll
        for (int n = 0; n < 4; ++n) {
            const int col = (int)brow0 + wcol * 64 + n * 16 + cl;
            const float bs = bias[col];
            const int ecol = n * 16 + cl;
#pragma unroll
            for (int ml = 0; ml < 2; ++ml) {
                const int m = h * 2 + ml;
                float g0 = acc[m][n][0] + bs, g1 = acc[m][n][1] + bs;
                float g2 = acc[m][n][2] + bs, g3 = acc[m][n][3] + bs;
                if (GELU) { g0 = gelu_t(g0); g1 = gelu_t(g1); g2 = gelu_t(g2); g3 = gelu_t(g3); }
                unsigned p01, p23;
                asm("v_cvt_pk_bf16_f32 %0, %1, %2" : "=v"(p01) : "v"(g0), "v"(g1));
                asm("v_cvt_pk_bf16_f32 %0, %1, %2" : "=v"(p23) : "v"(g2), "v"(g3));
                const int r0 = ml * 16 + rl;
                E[(r0 + 0) * 72 + ecol] = (short)(p01 & 0xffff);
                E[(r0 + 1) * 72 + ecol] = (short)(p01 >> 16);
                E[(r0 + 2) * 72 + ecol] = (short)(p23 & 0xffff);
                E[(r0 + 3) * 72 + ecol] = (short)(p23 >> 16);
            }
        }
        // wave-private region: LDS ops in-order within a wave
#pragma unroll
        for (int chunk = 0; chunk < 4; ++chunk) {
            const int rloc = chunk * 8 + (lane >> 3);
            const int c0   = (lane & 7) * 8;
            short8 v = *(const short8*)&E[rloc * 72 + c0];
            *(short8*)&C[(arow0 + wrow * 128 + h * 32 + rloc) * 512
                         + brow0 + wcol * 64 + c0] = v;
        }
    }
}

// ---- transpose+convert: dst[n][k] = bf16(src[k][n]), one 512x512 per blockIdx.z ----
__global__ __launch_bounds__(256)
void transpose_conv(const float* __restrict__ src, short* __restrict__ dst) {
    __shared__ float t[32][33];
    const long moff = (long)blockIdx.z * 512 * 512;
    const float* s = src + moff;
    short* d = dst + moff;
    const int tx = threadIdx.x & 31, ty = threadIdx.x >> 5;
    const int bi = blockIdx.x, bj = blockIdx.y;
#pragma unroll
    for (int j = 0; j < 4; ++j)
        t[ty + j * 8][tx] = s[(long)(bi * 32 + ty + j * 8) * 512 + bj * 32 + tx];
    __syncthreads();
#pragma unroll
    for (int j = 0; j < 4; ++j)
        d[(long)(bj * 32 + ty + j * 8) * 512 + bi * 32 + tx] = f2b(t[tx][ty + j * 8]);
}

// ---- f32 -> bf16 elementwise ----
__global__ __launch_bounds__(256)
void conv_f32_bf16(const float* __restrict__ src, short* __restrict__ dst, long n) {
    long i = ((long)blockIdx.x * 256 + threadIdx.x) * 4;
    if (i >= n) return;
    float4 f = *(const float4*)&src[i];
    short4v o;
    o[0] = f2b(f.x); o[1] = f2b(f.y); o[2] = f2b(f.z); o[3] = f2b(f.w);
    *(short4v*)&dst[i] = o;
}

// ---- bias fold: bB[(k+1)*512+n] = dot(tb3_k, eW1[:,n]) + eb1[n] ----
__global__ __launch_bounds__(256)
void bias_fold(const float* __restrict__ tb3, const short* __restrict__ wtE1,
               const float* __restrict__ eb1, float* __restrict__ bB) {
    const int wid = threadIdx.x >> 6, lane = threadIdx.x & 63;
    const int idx = blockIdx.x * 4 + wid;        // 0 .. 11*512-1
    const int k = idx >> 9, n = idx & 511;
    short8 wv = *(const short8*)&wtE1[(long)n * 512 + lane * 8];
    const float* tb = tb3 + (long)k * 512 + lane * 8;
    float s = 0.f;
#pragma unroll
    for (int j = 0; j < 8; ++j) s += b2f(wv[j]) * tb[j];
#pragma unroll
    for (int o = 1; o < 64; o <<= 1) s += __shfl_xor(s, o, 64);
    if (lane == 0) bB[(long)(k + 1) * 512 + n] = s + eb1[n];
}

// ---- fused LN + L2-normalize + MFMA Gram + logsumexp loss (r12-proven) ----
__global__ __launch_bounds__(256)
void ln_loss(const short* __restrict__ H, const float* __restrict__ g,
             const float* __restrict__ bta, float* __restrict__ out, int CH) {
    __shared__ alignas(16) short Z[4][16 * 520];
    const int wid = threadIdx.x >> 6, lane = threadIdx.x & 63;
    const long b = (long)blockIdx.x * 4 + wid;
    short* Zw = &Z[wid][0];

#pragma unroll
    for (int r = 12; r < 16; ++r)
        *(short8*)&Zw[r * 520 + lane * 8] = (short8){0, 0, 0, 0, 0, 0, 0, 0};

    for (int s = 0; s < 12; ++s) {
        short8 t = *(const short8*)&H[((long)s * CH + b) * 512 + lane * 8];
        float v[8];
        float sum = 0.f, ss = 0.f;
#pragma unroll
        for (int j = 0; j < 8; ++j) { v[j] = b2f(t[j]); sum += v[j]; ss += v[j] * v[j]; }
#pragma unroll
        for (int o = 1; o < 64; o <<= 1) { sum += __shfl_xor(sum, o, 64); ss += __shfl_xor(ss, o, 64); }
        const float mu = sum * (1.f / 512.f);
        const float rs = rsqrtf(ss * (1.f / 512.f) - mu * mu + 1e-5f);
        float y[8]; float nsq = 0.f;
#pragma unroll
        for (int j = 0; j < 8; ++j) {
            const int col = lane * 8 + j;
            y[j] = (v[j] - mu) * rs * g[col] + bta[col];
            nsq += y[j] * y[j];
        }
#pragma unroll
        for (int o = 1; o < 64; o <<= 1) nsq += __shfl_xor(nsq, o, 64);
        const float inv = 1.f / fmaxf(sqrtf(nsq), 1e-8f);
        short8 o8;
#pragma unroll
        for (int j = 0; j < 8; ++j) o8[j] = f2b(y[j] * inv);
        *(short8*)&Zw[s * 520 + lane * 8] = o8;
    }

    f32x4 acc = {0.f, 0.f, 0.f, 0.f};
    const int lr = lane & 15, hi = lane >> 4;
#pragma unroll
    for (int st = 0; st < 16; ++st) {
        short8 a = *(const short8*)&Zw[lr * 520 + st * 32 + hi * 8];
        acc = __builtin_amdgcn_mfma_f32_16x16x32_bf16(a, a, acc, 0, 0, 0);
    }
    const int col = lr;
    float lmax = -3.0e38f;
    bool valid[4];
#pragma unroll
    for (int i = 0; i < 4; ++i) {
        const int row = hi * 4 + i;
        valid[i] = (row < 12) && (row != col);
        if (valid[i]) lmax = fmaxf(lmax, acc[i]);
    }
    lmax = fmaxf(lmax, __shfl_xor(lmax, 16, 64));
    lmax = fmaxf(lmax, __shfl_xor(lmax, 32, 64));
    float esum = 0.f;
#pragma unroll
    for (int i = 0; i < 4; ++i)
        if (valid[i]) esum += __builtin_amdgcn_exp2f((acc[i] - lmax) * 1.44269504f);
    esum += __shfl_xor(esum, 16, 64);
    esum += __shfl_xor(esum, 32, 64);
    float contrib = 0.f;
    if (hi == 0 && col >= 1 && col <= 11) {
        const float logden = lmax + __builtin_amdgcn_logf(esum) * 0.6931471806f;
        contrib = acc[0] - logden;
    }
#pragma unroll
    for (int o = 1; o < 16; o <<= 1) contrib += __shfl_xor(contrib, o, 64);
    if (lane == 0) out[b] = -contrib;
}

// ---------------- host ----------------
extern "C" void kernel_launch(void* const* d_in, const int* in_sizes, int n_in,
                              void* d_out, int out_size, void* d_ws, size_t ws_size,
                              hipStream_t stream) {
    const float* x    = (const float*)d_in[0];
    const float* tW1  = (const float*)d_in[1];
    const float* tb1  = (const float*)d_in[2];
    const float* tW2  = (const float*)d_in[3];
    const float* tb2  = (const float*)d_in[4];
    const float* tW3  = (const float*)d_in[5];
    const float* tb3  = (const float*)d_in[6];
    const float* eW1  = (const float*)d_in[7];
    const float* eb1  = (const float*)d_in[8];
    const float* eW2  = (const float*)d_in[9];
    const float* eb2  = (const float*)d_in[10];
    const float* eW3  = (const float*)d_in[11];
    const float* eb3  = (const float*)d_in[12];
    const float* ln_g = (const float*)d_in[13];
    const float* ln_b = (const float*)d_in[14];

    const int  B    = in_sizes[0] / 512;   // 16384
    const long WMAT = 512L * 512L;

    int  c  = 1;
    long CH = B;
    for (;;) {
        CH = (long)B / c;
        size_t need = (size_t)48 * WMAT * 2 + (512 + 12 * 512) * 4
                    + (size_t)24 * CH * 512 * 2 + 8192;
        if (need <= ws_size || CH <= 256) break;
        c <<= 1;
    }
    const long SLAB = 12L * CH * 512;

    short* wt   = (short*)d_ws;             // 0..21: tW1^T,tW2^T; 22..32: tW3 (orig); 33..35: eW^T
    short* Mt   = wt + 36L * WMAT;          // slot0 = eW1^T, 1..11 = (tW3_k·eW1)^T
    float* zero512 = (float*)(Mt + 12L * WMAT);
    float* bB   = zero512 + 512;            // 12x512 folded biases
    short* S    = (short*)(bB + 12 * 512);  // slab S [12, CH, 512]
    short* T    = S + SLAB;                 // slab T [12, CH, 512]

    // --- weight prep (once per launch) ---
    {
        dim3 tgK(16, 16, 11), tg1(16, 16, 1);
        transpose_conv<<<tgK, 256, 0, stream>>>(tW1, wt + 0L * WMAT);
        transpose_conv<<<tgK, 256, 0, stream>>>(tW2, wt + 11L * WMAT);
        conv_f32_bf16<<<(unsigned)((11 * WMAT / 4 + 255) / 256), 256, 0, stream>>>(
            tW3, wt + 22L * WMAT, 11 * WMAT);
        transpose_conv<<<tg1, 256, 0, stream>>>(eW1, wt + 33L * WMAT);
        transpose_conv<<<tg1, 256, 0, stream>>>(eW2, wt + 34L * WMAT);
        transpose_conv<<<tg1, 256, 0, stream>>>(eW3, wt + 35L * WMAT);

        hipMemsetAsync(zero512, 0, 512 * sizeof(float), stream);
        gemm_bt<false><<<dim3(4, 1, 11), 512, 0, stream>>>(
            wt + 33L * WMAT, 0, wt + 22L * WMAT, WMAT, zero512, 0, Mt + WMAT, WMAT);
        hipMemcpyAsync(Mt, wt + 33L * WMAT, WMAT * sizeof(short),
                       hipMemcpyDeviceToDevice, stream);
        hipMemcpyAsync(bB, eb1, 512 * sizeof(float),
                       hipMemcpyDeviceToDevice, stream);
        bias_fold<<<(11 * 512) / 4, 256, 0, stream>>>(tb3, wt + 33L * WMAT, eb1, bB);
    }

    const long SC = CH * 512;
    const dim3 gT((unsigned)(CH / 256 * 2), 1, 11);       // L1,L2: M = CH
    const dim3 gF((unsigned)(CH / 256 * 2), 1, 12);       // fold pass: 12 views
    const dim3 gE((unsigned)(12 * CH / 256 * 2), 1, 1);   // E2,E3: M = 12*CH

    for (int ch = 0; ch < c; ++ch) {
        conv_f32_bf16<<<(unsigned)((SC / 4 + 255) / 256), 256, 0, stream>>>(
            x + (long)ch * SC, S, SC);

        gemm_bt<true ><<<gT, 512, 0, stream>>>(S, 0,  wt + 0L * WMAT,  WMAT, tb1, 512, T + SC, SC);
        gemm_bt<true ><<<gT, 512, 0, stream>>>(T + SC, SC, wt + 11L * WMAT, WMAT, tb2, 512, S + SC, SC);
        gemm_bt<true ><<<gF, 512, 0, stream>>>(S, SC, Mt, WMAT, bB, 512, T, SC);
        gemm_bt<true ><<<gE, 512, 0, stream>>>(T, 0, wt + 34L * WMAT, 0, eb2, 0, S, 0);
        gemm_bt<false><<<gE, 512, 0, stream>>>(S, 0, wt + 35L * WMAT, 0, eb3, 0, T, 0);

        ln_loss<<<(unsigned)(CH / 4), 256, 0, stream>>>(
            T, ln_g, ln_b, (float*)d_out + (long)ch * CH, (int)CH);
    }
}